// Round 4
// baseline (42.013 us; speedup 1.0000x reference)
//
#include <hip/hip_runtime.h>

#pragma clang fp contract(off)

typedef unsigned long long u64;

#define TOPK 5
#define WAVES 4   // waves per block; one block per (b, gt) task

// branchless compare-exchange on u64 keys (ascending) — pure selects
#define CE(x, y) do { const u64 _a = (x), _b = (y); const bool _l = _b < _a; \
                      (x) = _l ? _b : _a; (y) = _l ? _a : _b; } while (0)

// fully branchless sorted-insert of nk into ascending 5-list.
// 5 u64 compares + 9 u64 selects; strict < preserves (cost,index) tie-break.
#define INSERT(nk, k0, k1, k2, k3, k4) do {        \
    const u64 _n = (nk);                           \
    const bool l0 = _n < k0;                       \
    const bool l1 = _n < k1;                       \
    const bool l2 = _n < k2;                       \
    const bool l3 = _n < k3;                       \
    const bool l4 = _n < k4;                       \
    k4 = l4 ? (l3 ? k3 : _n) : k4;                 \
    k3 = l3 ? (l2 ? k2 : _n) : k3;                 \
    k2 = l2 ? (l1 ? k1 : _n) : k2;                 \
    k1 = l1 ? (l0 ? k0 : _n) : k1;                 \
    k0 = l0 ? _n : k0;                             \
} while (0)

// Markstein-refined division: rcp + NR + quotient correction (bit-exact vs IEEE
// div in practice; verified absmax 0.0 in R3).
__device__ __forceinline__ float fast_div(float a, float b) {
    float r = __builtin_amdgcn_rcpf(b);
    r = fmaf(fmaf(-b, r, 1.0f), r, r);
    float q = a * r;
    q = fmaf(fmaf(-b, q, a), r, q);
    return q;
}

__device__ __forceinline__ u64 eval_key(const float4 pb, const float4 gb,
                                        const float g_area, const int p) {
    const float area_p = (pb.z - pb.x) * (pb.w - pb.y);
    const float cost_bbox = fabsf(pb.x - gb.x) + fabsf(pb.y - gb.y)
                          + fabsf(pb.z - gb.z) + fabsf(pb.w - gb.w);
    // intersection
    const float ltx = fmaxf(pb.x, gb.x), lty = fmaxf(pb.y, gb.y);
    const float rbx = fminf(pb.z, gb.z), rby = fminf(pb.w, gb.w);
    const float iw = fmaxf(rbx - ltx, 0.0f), ih = fmaxf(rby - lty, 0.0f);
    const float inter = iw * ih;
    const float uni = area_p + g_area - inter;
    const float iou = fast_div(inter, uni);
    // enclosing box (rb_e - lt_e >= 0 always for valid xyxy -> clip is identity)
    const float ex1 = fminf(pb.x, gb.x), ey1 = fminf(pb.y, gb.y);
    const float ex2 = fmaxf(pb.z, gb.z), ey2 = fmaxf(pb.w, gb.w);
    const float area_e = (ex2 - ex1) * (ey2 - ey1);
    const float giou = iou - fast_div(area_e - uni, area_e);
    const float cost = cost_bbox + (1.0f - giou);
    return ((u64)__float_as_uint(cost) << 32) | (unsigned)p;
}

__global__ __launch_bounds__(64 * WAVES) void matcher_topk_kernel(
    const float* __restrict__ pred_box,  // [B, NP, 4]
    const float* __restrict__ gt_box,    // [B, NG, 4]
    int* __restrict__ out_pred,          // [B, NG*TOPK]
    int* __restrict__ out_gt,            // [B, NG*TOPK]
    int B, int NP, int NG)
{
    const int task = blockIdx.x;              // one block per (b, m)
    const int wid  = threadIdx.x >> 6;
    const int lane = threadIdx.x & 63;
    const int b = task / NG;
    const int m = task - b * NG;

    const float4 gb = ((const float4*)gt_box)[b * NG + m];
    const float g_area = (gb.z - gb.x) * (gb.w - gb.y);

    // sorted ascending top-5 keys; key = (cost_bits<<32) | pred_idx  (cost>=0)
    u64 k0 = ~0ULL, k1 = ~0ULL, k2 = ~0ULL, k3 = ~0ULL, k4 = ~0ULL;

    const float4* pbase = (const float4*)pred_box + (size_t)b * NP;

    int p = threadIdx.x;
    // unroll x2: two independent load+cost chains per iteration
    for (; p + 256 < NP; p += 512) {
        const float4 pA = pbase[p];
        const float4 pB = pbase[p + 256];
        const u64 kA = eval_key(pA, gb, g_area, p);
        const u64 kB = eval_key(pB, gb, g_area, p + 256);
        INSERT(kA, k0, k1, k2, k3, k4);
        INSERT(kB, k0, k1, k2, k3, k4);
    }
    if (p < NP) {
        const float4 pA = pbase[p];
        const u64 kA = eval_key(pA, gb, g_area, p);
        INSERT(kA, k0, k1, k2, k3, k4);
    }

    // wave butterfly: merge sorted 5-lists across all 64 lanes
    #pragma unroll
    for (int off = 1; off < 64; off <<= 1) {
        const u64 b0 = __shfl_xor(k0, off);
        const u64 b1 = __shfl_xor(k1, off);
        const u64 b2 = __shfl_xor(k2, off);
        const u64 b3 = __shfl_xor(k3, off);
        const u64 b4 = __shfl_xor(k4, off);
        u64 m0 = k0 < b4 ? k0 : b4;
        u64 m1 = k1 < b3 ? k1 : b3;
        u64 m2 = k2 < b2 ? k2 : b2;
        u64 m3 = k3 < b1 ? k3 : b1;
        u64 m4 = k4 < b0 ? k4 : b0;
        CE(m0, m1); CE(m3, m4); CE(m2, m4); CE(m2, m3); CE(m1, m4);
        CE(m0, m3); CE(m0, m2); CE(m1, m3); CE(m1, m2);
        k0 = m0; k1 = m1; k2 = m2; k3 = m3; k4 = m4;
    }

    // cross-wave merge via LDS (4 sorted 5-lists -> final 5)
    __shared__ u64 lds[WAVES][TOPK];
    if (lane == 0) {
        lds[wid][0] = k0; lds[wid][1] = k1; lds[wid][2] = k2;
        lds[wid][3] = k3; lds[wid][4] = k4;
    }
    __syncthreads();

    if (threadIdx.x == 0) {
        int head[WAVES];
        #pragma unroll
        for (int w = 0; w < WAVES; ++w) head[w] = 0;
        const int base = task * TOPK;
        #pragma unroll
        for (int r = 0; r < TOPK; ++r) {
            u64 best = ~0ULL; int bw = 0;
            #pragma unroll
            for (int w = 0; w < WAVES; ++w) {
                const u64 v = lds[w][head[w]];
                if (v < best) { best = v; bw = w; }
            }
            head[bw]++;
            out_pred[base + r] = (int)(unsigned)(best & 0xFFFFFFFFu);
            out_gt[base + r]   = m;
        }
    }
}

extern "C" void kernel_launch(void* const* d_in, const int* in_sizes, int n_in,
                              void* d_out, int out_size, void* d_ws, size_t ws_size,
                              hipStream_t stream) {
    const float* pred_box = (const float*)d_in[0];   // [B, NP, 4]
    const float* gt_box   = (const float*)d_in[2];   // [B, NG, 4]

    const int NP = 5000;
    const int B  = in_sizes[1] / NP;                 // pred_obj is [B, NP]
    const int NG = in_sizes[3] / B;                  // gt_obj is [B, NG]

    int* out_pred = (int*)d_out;
    int* out_gt   = out_pred + B * NG * TOPK;

    const int total = B * NG;                        // one block per task
    hipLaunchKernelGGL(matcher_topk_kernel, dim3(total), dim3(64 * WAVES), 0, stream,
                       pred_box, gt_box, out_pred, out_gt, B, NP, NG);
}

// Round 5
// 41.270 us; speedup vs baseline: 1.0180x; 1.0180x over previous
//
#include <hip/hip_runtime.h>

#pragma clang fp contract(off)

typedef unsigned long long u64;

#define TOPK 5
#define WAVES 4   // waves per block; one block per (b, gt) task

// branchless compare-exchange on u64 keys (ascending) — pure selects
#define CE(x, y) do { const u64 _a = (x), _b = (y); const bool _l = _b < _a; \
                      (x) = _l ? _b : _a; (y) = _l ? _a : _b; } while (0)

// fully branchless sorted-insert of nk into ascending 5-list (tail path only)
#define INSERT(nk, k0, k1, k2, k3, k4) do {        \
    const u64 _n = (nk);                           \
    const bool l0 = _n < k0;                       \
    const bool l1 = _n < k1;                       \
    const bool l2 = _n < k2;                       \
    const bool l3 = _n < k3;                       \
    const bool l4 = _n < k4;                       \
    k4 = l4 ? (l3 ? k3 : _n) : k4;                 \
    k3 = l3 ? (l2 ? k2 : _n) : k3;                 \
    k2 = l2 ? (l1 ? k1 : _n) : k2;                 \
    k1 = l1 ? (l0 ? k0 : _n) : k1;                 \
    k0 = l0 ? _n : k0;                             \
} while (0)

// Markstein-refined division (verified bit-exact vs reference: absmax 0.0)
__device__ __forceinline__ float fast_div(float a, float b) {
    float r = __builtin_amdgcn_rcpf(b);
    r = fmaf(fmaf(-b, r, 1.0f), r, r);
    float q = a * r;
    q = fmaf(fmaf(-b, q, a), r, q);
    return q;
}

__device__ __forceinline__ u64 eval_key(const float4 pb, const float4 gb,
                                        const float g_area, const int p) {
    const float area_p = (pb.z - pb.x) * (pb.w - pb.y);
    const float cost_bbox = fabsf(pb.x - gb.x) + fabsf(pb.y - gb.y)
                          + fabsf(pb.z - gb.z) + fabsf(pb.w - gb.w);
    const float ltx = fmaxf(pb.x, gb.x), lty = fmaxf(pb.y, gb.y);
    const float rbx = fminf(pb.z, gb.z), rby = fminf(pb.w, gb.w);
    const float iw = fmaxf(rbx - ltx, 0.0f), ih = fmaxf(rby - lty, 0.0f);
    const float inter = iw * ih;
    const float uni = area_p + g_area - inter;
    const float iou = fast_div(inter, uni);
    const float ex1 = fminf(pb.x, gb.x), ey1 = fminf(pb.y, gb.y);
    const float ex2 = fmaxf(pb.z, gb.z), ey2 = fmaxf(pb.w, gb.w);
    const float area_e = (ex2 - ex1) * (ey2 - ey1);
    const float giou = iou - fast_div(area_e - uni, area_e);
    const float cost = cost_bbox + (1.0f - giou);
    return ((u64)__float_as_uint(cost) << 32) | (unsigned)p;
}

__global__ __launch_bounds__(64 * WAVES) void matcher_topk_kernel(
    const float* __restrict__ pred_box,  // [B, NP, 4]
    const float* __restrict__ gt_box,    // [B, NG, 4]
    int* __restrict__ out_pred,          // [B, NG*TOPK]
    int* __restrict__ out_gt,            // [B, NG*TOPK]
    int B, int NP, int NG)
{
    const int task = blockIdx.x;              // one block per (b, m)
    const int wid  = threadIdx.x >> 6;
    const int lane = threadIdx.x & 63;
    const int b = task / NG;
    const int m = task - b * NG;

    const float4 gb = ((const float4*)gt_box)[b * NG + m];
    const float g_area = (gb.z - gb.x) * (gb.w - gb.y);

    u64 k0 = ~0ULL, k1 = ~0ULL, k2 = ~0ULL, k3 = ~0ULL, k4 = ~0ULL;

    const float4* pbase = (const float4*)pred_box + (size_t)b * NP;

    int p = threadIdx.x;
    // unroll x4: four independent load+cost chains, then ONE batched merge
    for (; p + 768 < NP; p += 1024) {
        const float4 pA = pbase[p];
        const float4 pB = pbase[p + 256];
        const float4 pC = pbase[p + 512];
        const float4 pD = pbase[p + 768];
        u64 kA = eval_key(pA, gb, g_area, p);
        u64 kB = eval_key(pB, gb, g_area, p + 256);
        u64 kC = eval_key(pC, gb, g_area, p + 512);
        u64 kD = eval_key(pD, gb, g_area, p + 768);
        // sort4 (independent of k-state -> ILP): kA<=kB<=kC<=kD
        CE(kA, kB); CE(kC, kD); CE(kA, kC); CE(kB, kD); CE(kB, kC);
        // bitonic lower-5 merge of sorted-5 (k0..k4) with sorted-4 (kA..kD, pad inf)
        u64 m0 = k0;                      // min(k0, +inf)
        u64 m1 = k1 < kD ? k1 : kD;
        u64 m2 = k2 < kC ? k2 : kC;
        u64 m3 = k3 < kB ? k3 : kB;
        u64 m4 = k4 < kA ? k4 : kA;
        // sort5 cleanup (9 CE)
        CE(m0, m1); CE(m3, m4); CE(m2, m4); CE(m2, m3); CE(m1, m4);
        CE(m0, m3); CE(m0, m2); CE(m1, m3); CE(m1, m2);
        k0 = m0; k1 = m1; k2 = m2; k3 = m3; k4 = m4;
    }
    for (; p < NP; p += 256) {
        const float4 pA = pbase[p];
        const u64 kA = eval_key(pA, gb, g_area, p);
        INSERT(kA, k0, k1, k2, k3, k4);
    }

    // wave butterfly: merge sorted 5-lists across all 64 lanes
    #pragma unroll
    for (int off = 1; off < 64; off <<= 1) {
        const u64 b0 = __shfl_xor(k0, off);
        const u64 b1 = __shfl_xor(k1, off);
        const u64 b2 = __shfl_xor(k2, off);
        const u64 b3 = __shfl_xor(k3, off);
        const u64 b4 = __shfl_xor(k4, off);
        u64 m0 = k0 < b4 ? k0 : b4;
        u64 m1 = k1 < b3 ? k1 : b3;
        u64 m2 = k2 < b2 ? k2 : b2;
        u64 m3 = k3 < b1 ? k3 : b1;
        u64 m4 = k4 < b0 ? k4 : b0;
        CE(m0, m1); CE(m3, m4); CE(m2, m4); CE(m2, m3); CE(m1, m4);
        CE(m0, m3); CE(m0, m2); CE(m1, m3); CE(m1, m2);
        k0 = m0; k1 = m1; k2 = m2; k3 = m3; k4 = m4;
    }

    // cross-wave merge via LDS (4 sorted 5-lists -> final 5)
    __shared__ u64 lds[WAVES][TOPK];
    if (lane == 0) {
        lds[wid][0] = k0; lds[wid][1] = k1; lds[wid][2] = k2;
        lds[wid][3] = k3; lds[wid][4] = k4;
    }
    __syncthreads();

    if (threadIdx.x == 0) {
        int head[WAVES];
        #pragma unroll
        for (int w = 0; w < WAVES; ++w) head[w] = 0;
        const int base = task * TOPK;
        #pragma unroll
        for (int r = 0; r < TOPK; ++r) {
            u64 best = ~0ULL; int bw = 0;
            #pragma unroll
            for (int w = 0; w < WAVES; ++w) {
                const u64 v = lds[w][head[w]];
                if (v < best) { best = v; bw = w; }
            }
            head[bw]++;
            out_pred[base + r] = (int)(unsigned)(best & 0xFFFFFFFFu);
            out_gt[base + r]   = m;
        }
    }
}

extern "C" void kernel_launch(void* const* d_in, const int* in_sizes, int n_in,
                              void* d_out, int out_size, void* d_ws, size_t ws_size,
                              hipStream_t stream) {
    const float* pred_box = (const float*)d_in[0];   // [B, NP, 4]
    const float* gt_box   = (const float*)d_in[2];   // [B, NG, 4]

    const int NP = 5000;
    const int B  = in_sizes[1] / NP;                 // pred_obj is [B, NP]
    const int NG = in_sizes[3] / B;                  // gt_obj is [B, NG]

    int* out_pred = (int*)d_out;
    int* out_gt   = out_pred + B * NG * TOPK;

    const int total = B * NG;                        // one block per task
    hipLaunchKernelGGL(matcher_topk_kernel, dim3(total), dim3(64 * WAVES), 0, stream,
                       pred_box, gt_box, out_pred, out_gt, B, NP, NG);
}